// Round 7
// baseline (219.644 us; speedup 1.0000x reference)
//
#include <hip/hip_runtime.h>

#define N_NODES 50000
#define N_EDGES 200000
#define IN1_SIZE 160
#define W_SIZE 224
#define OUT_SIZE 480
#define RCHUNK 8
#define INV_SQRT3 0.5773502691896258f
#define INV_SQRT2 0.7071067811865476f

// ---------------- CSR build ----------------
__global__ void hist_kernel(const int* __restrict__ dst, int* __restrict__ counts) {
    int i = blockIdx.x * blockDim.x + threadIdx.x;
    if (i < N_EDGES) atomicAdd(&counts[dst[i]], 1);
}

__global__ __launch_bounds__(1024) void scan_blocks_kernel(
    const int* __restrict__ counts, int* __restrict__ offsets,
    int* __restrict__ partials)
{
    __shared__ int sm[1024];
    const int t = threadIdx.x;
    const int gid = blockIdx.x * 1024 + t;
    const int v = (gid < N_NODES) ? counts[gid] : 0;
    sm[t] = v;
    __syncthreads();
    for (int off = 1; off < 1024; off <<= 1) {
        int a = (t >= off) ? sm[t - off] : 0;
        __syncthreads();
        sm[t] += a;
        __syncthreads();
    }
    if (gid < N_NODES) offsets[gid] = sm[t] - v;
    if (t == 1023) partials[blockIdx.x] = sm[1023];
}

__global__ __launch_bounds__(1024) void add_partials_kernel(
    const int* __restrict__ partials, int* __restrict__ offsets,
    int* __restrict__ cursor)
{
    const int blk = blockIdx.x;
    const int gid = blk * 1024 + threadIdx.x;
    int s = 0;
    for (int j = 0; j < blk; ++j) s += partials[j];
    if (gid < N_NODES) {
        const int o = offsets[gid] + s;
        offsets[gid] = o;
        cursor[gid]  = o;
    }
}

// meta[pos] = {edge_id, src, dst, 0}; ys[pos] = in2 row
__global__ void fill_kernel(const int* __restrict__ dst, const int* __restrict__ src,
                            const float4* __restrict__ in2,
                            int* __restrict__ cursor, int4* __restrict__ meta,
                            float4* __restrict__ ys) {
    int i = blockIdx.x * blockDim.x + threadIdx.x;
    if (i < N_EDGES) {
        int d = dst[i];
        int pos = atomicAdd(&cursor[d], 1);
        meta[pos] = make_int4(i, src[i], d, 0);
        ys[pos] = in2[i];
    }
}

// Zero rows that get atomic adds (segment crosses chunk boundary) or deg==0.
__global__ __launch_bounds__(256) void zero_rows_kernel(
    const int* __restrict__ counts, const int* __restrict__ offsets,
    float* __restrict__ out)
{
    const int wave = threadIdx.x >> 6;
    const int lane = threadIdx.x & 63;
    const int n = blockIdx.x * 4 + wave;
    if (n >= N_NODES) return;
    const int cnt = counts[n];
    const int start = offsets[n];
    const bool nz = (cnt == 0) || ((start >> 3) != ((start + cnt - 1) >> 3));
    if (!nz) return;
    float* __restrict__ row = out + (long)n * OUT_SIZE;
    #pragma unroll
    for (int j = 0; j < 8; ++j) {
        const int idx = lane + (j << 6);
        if (idx < OUT_SIZE) row[idx] = 0.f;
    }
}

// ---------------- main: one wave per 8 sorted edges, all loads up-front ----------------
__global__ __launch_bounds__(256) void tp_chunk8_kernel(
    const float*  __restrict__ in1,
    const float*  __restrict__ weight,
    const int4*   __restrict__ meta,
    const float4* __restrict__ ys,
    float*        __restrict__ out)
{
    const int lane = threadIdx.x & 63;
    const int u = lane & 31;
    const int h = lane >> 5;
    const int wid = blockIdx.x * 4 + (threadIdx.x >> 6);
    const int p0 = __builtin_amdgcn_readfirstlane(wid * RCHUNK);
    if (p0 >= N_EDGES) return;

    // ---- scalar metadata for 8 edges ----
    int4   m_[RCHUNK];
    float4 y_[RCHUNK];
    #pragma unroll
    for (int t = 0; t < RCHUNK; ++t) {
        m_[t] = meta[p0 + t];
        y_[t] = ys[p0 + t];
    }
    const int d_prev = (p0 > 0) ? meta[p0 - 1].z : -1;
    const int d_next = (p0 + RCHUNK < N_EDGES) ? meta[p0 + RCHUNK].z : -1;
    const bool head_shared = (d_prev == m_[0].z);
    const bool tail_shared = (d_next == m_[RCHUNK - 1].z);

    // ---- vector loads for 8 edges: 6 coalesced loads each, all independent ----
    float xs_[RCHUNK], a_[RCHUNK], bd_[RCHUNK], w1_[RCHUNK], w2_[RCHUNK], c_[RCHUNK];
    #pragma unroll
    for (int t = 0; t < RCHUNK; ++t) {
        const float* __restrict__ x = in1 + (long)m_[t].y * IN1_SIZE;
        const float* __restrict__ w = weight + (long)m_[t].x * W_SIZE;
        xs_[t] = x[lane];                                   // s1
        a_[t]  = x[64 + lane];                              // v floats 0..63
        bd_[t] = (h == 0) ? x[128 + u] : w[192 + u];        // v floats 64..95 | w5
        w1_[t] = w[lane];
        w2_[t] = w[64 + lane];
        c_[t]  = w[128 + lane];                             // w3|w4 packed
    }

    // output offsets for this lane
    const int off0 = lane;
    const int off1 = 96 + 3 * lane;
    const int off4 = 64 + u;
    const int off5 = (h ? 384 : 288) + 3 * u;

    float acc0 = 0.f, acc1 = 0.f, acc2 = 0.f, acc3 = 0.f;
    float acc4 = 0.f, acc5 = 0.f, acc6 = 0.f, acc7 = 0.f;

    auto flush = [&](int node, bool use_atomic) {
        float* __restrict__ row = out + (long)node * OUT_SIZE;
        if (use_atomic) {
            atomicAdd(row + off0,     acc0);
            atomicAdd(row + off1,     acc1);
            atomicAdd(row + off1 + 1, acc2);
            atomicAdd(row + off1 + 2, acc3);
            if (h == 0) atomicAdd(row + off4, acc4);
            atomicAdd(row + off5,     acc5);
            atomicAdd(row + off5 + 1, acc6);
            atomicAdd(row + off5 + 2, acc7);
        } else {
            row[off0]     = acc0;
            row[off1]     = acc1;
            row[off1 + 1] = acc2;
            row[off1 + 2] = acc3;
            if (h == 0) row[off4] = acc4;
            row[off5]     = acc5;
            row[off5 + 1] = acc6;
            row[off5 + 2] = acc7;
        }
        acc0 = acc1 = acc2 = acc3 = acc4 = acc5 = acc6 = acc7 = 0.f;
    };

    int cur = m_[0].z;
    bool first = true;

    #pragma unroll
    for (int t = 0; t < RCHUNK; ++t) {
        if (m_[t].z != cur) {
            flush(cur, first && head_shared);
            first = false;
            cur = m_[t].z;
        }
        const float y0 = y_[t].x, yx = y_[t].y, yy = y_[t].z, yz = y_[t].w;

        // reconstruct v1[u][*], w3, w4, w5 via cross-lane shuffles
        const int j0 = 3 * u;
        float v0, v1, v2;
        {
            const float s0a = __shfl(a_[t], j0 & 63);
            const float s0b = __shfl(bd_[t], j0 & 63);
            v0 = (j0 < 64) ? s0a : s0b;
            const float s1a = __shfl(a_[t], (j0 + 1) & 63);
            const float s1b = __shfl(bd_[t], (j0 + 1) & 63);
            v1 = (j0 + 1 < 64) ? s1a : s1b;
            const float s2a = __shfl(a_[t], (j0 + 2) & 63);
            const float s2b = __shfl(bd_[t], (j0 + 2) & 63);
            v2 = (j0 + 2 < 64) ? s2a : s2b;
        }
        const float w3 = __shfl(c_[t], u);
        const float w4 = __shfl(c_[t], u + 32);
        const float w5 = __shfl(bd_[t], 32 + u);

        acc0 += w1_[t] * xs_[t] * y0;
        const float sw2 = w2_[t] * xs_[t];
        acc1 += sw2 * yx;
        acc2 += sw2 * yy;
        acc3 += sw2 * yz;
        if (h == 0) {
            acc4 += w4 * (v0 * yx + v1 * yy + v2 * yz) * INV_SQRT3;
            const float wy = w3 * y0;
            acc5 += wy * v0;
            acc6 += wy * v1;
            acc7 += wy * v2;
        } else {
            const float wc = w5 * INV_SQRT2;
            acc5 += wc * (v1 * yz - v2 * yy);
            acc6 += wc * (v2 * yx - v0 * yz);
            acc7 += wc * (v0 * yy - v1 * yx);
        }
    }
    flush(cur, (first && head_shared) || tail_shared);
}

// ---------------- fallback path (R1, atomics, no ws needed) ----------------
__global__ void zero_out_kernel(float4* __restrict__ out, int n4) {
    const float4 z = make_float4(0.f, 0.f, 0.f, 0.f);
    for (int i = blockIdx.x * blockDim.x + threadIdx.x; i < n4;
         i += gridDim.x * blockDim.x) out[i] = z;
}

__device__ __forceinline__ float edge_val(
    int idx, const float* __restrict__ x, const float* __restrict__ w,
    float y0, float y1x, float y1y, float y1z)
{
    if (idx < 64) {
        return w[idx] * x[idx] * y0;
    } else if (idx < 96) {
        const int u = idx - 64;
        const float a0 = x[64 + 3 * u], a1 = x[65 + 3 * u], a2 = x[66 + 3 * u];
        return w[160 + u] * (a0 * y1x + a1 * y1y + a2 * y1z) * INV_SQRT3;
    } else if (idx < 288) {
        const int t = idx - 96;
        const int i = t / 3;
        const int k = t - 3 * i;
        const float yk = (k == 0) ? y1x : (k == 1) ? y1y : y1z;
        return w[64 + i] * x[i] * yk;
    } else if (idx < 384) {
        const int t = idx - 288;
        const int u = t / 3;
        const int k = t - 3 * u;
        return w[128 + u] * x[64 + 3 * u + k] * y0;
    } else {
        const int t = idx - 384;
        const int u = t / 3;
        const int k = t - 3 * u;
        const float a0 = x[64 + 3 * u], a1 = x[65 + 3 * u], a2 = x[66 + 3 * u];
        float cc;
        if (k == 0)      cc = a1 * y1z - a2 * y1y;
        else if (k == 1) cc = a2 * y1x - a0 * y1z;
        else             cc = a0 * y1y - a1 * y1x;
        return w[192 + u] * cc * INV_SQRT2;
    }
}

__global__ __launch_bounds__(256) void tp_scatter_kernel(
    const float* __restrict__ in1, const float* __restrict__ in2,
    const float* __restrict__ weight,
    const int* __restrict__ src, const int* __restrict__ dst,
    float* __restrict__ out)
{
    const int wave = threadIdx.x >> 6;
    const int lane = threadIdx.x & 63;
    const int e = blockIdx.x * 4 + wave;
    if (e >= N_EDGES) return;
    const int sn = src[e];
    const int dn = dst[e];
    const float* __restrict__ x = in1 + (long)sn * IN1_SIZE;
    const float* __restrict__ w = weight + (long)e * W_SIZE;
    const float y0  = in2[e * 4 + 0];
    const float y1x = in2[e * 4 + 1];
    const float y1y = in2[e * 4 + 2];
    const float y1z = in2[e * 4 + 3];
    float* __restrict__ o = out + (long)dn * OUT_SIZE;
    #pragma unroll
    for (int j = 0; j < 8; ++j) {
        const int idx = lane + (j << 6);
        if (idx < OUT_SIZE)
            atomicAdd(o + idx, edge_val(idx, x, w, y0, y1x, y1y, y1z));
    }
}

extern "C" void kernel_launch(void* const* d_in, const int* in_sizes, int n_in,
                              void* d_out, int out_size, void* d_ws, size_t ws_size,
                              hipStream_t stream) {
    const float* in1    = (const float*)d_in[0];
    const float* in2    = (const float*)d_in[1];
    const float* weight = (const float*)d_in[2];
    const int*   src    = (const int*)d_in[3];
    const int*   dst    = (const int*)d_in[4];
    float* out = (float*)d_out;

    // ws layout: ys[E] float4 | meta[E] int4 | counts[N] | offsets[N] | cursor[N] | partials[64]
    const size_t need = (size_t)N_EDGES * 32 +
                        (size_t)(3 * N_NODES + 64) * sizeof(int);
    if (ws_size >= need) {
        float4* ys     = (float4*)d_ws;
        int4*   meta   = (int4*)(ys + N_EDGES);
        int* counts    = (int*)(meta + N_EDGES);
        int* offsets   = counts + N_NODES;
        int* cursor    = offsets + N_NODES;
        int* partials  = cursor + N_NODES;

        const int nblk = (N_NODES + 1023) / 1024;   // 49

        hipMemsetAsync(counts, 0, N_NODES * sizeof(int), stream);
        hist_kernel<<<(N_EDGES + 255) / 256, 256, 0, stream>>>(dst, counts);
        scan_blocks_kernel<<<nblk, 1024, 0, stream>>>(counts, offsets, partials);
        add_partials_kernel<<<nblk, 1024, 0, stream>>>(partials, offsets, cursor);
        fill_kernel<<<(N_EDGES + 255) / 256, 256, 0, stream>>>(
            dst, src, (const float4*)in2, cursor, meta, ys);
        zero_rows_kernel<<<(N_NODES + 3) / 4, 256, 0, stream>>>(counts, offsets, out);

        const int nwaves = N_EDGES / RCHUNK;        // 25000
        tp_chunk8_kernel<<<(nwaves + 3) / 4, 256, 0, stream>>>(
            in1, weight, meta, ys, out);
    } else {
        const int n4 = out_size / 4;
        zero_out_kernel<<<2048, 256, 0, stream>>>((float4*)out, n4);
        tp_scatter_kernel<<<(N_EDGES + 3) / 4, 256, 0, stream>>>(
            in1, in2, weight, src, dst, out);
    }
}

// Round 8
// 126.588 us; speedup vs baseline: 1.7351x; 1.7351x over previous
//
#include <hip/hip_runtime.h>

#define N_NODES 50000
#define N_EDGES 200000
#define IN1_SIZE 160
#define W_SIZE 224
#define OUT_SIZE 480
#define INV_SQRT3 0.5773502691896258f
#define INV_SQRT2 0.7071067811865476f

// ---------------- CSR build ----------------
__global__ void hist_kernel(const int* __restrict__ dst, int* __restrict__ counts) {
    int i = blockIdx.x * blockDim.x + threadIdx.x;
    if (i < N_EDGES) atomicAdd(&counts[dst[i]], 1);
}

__global__ __launch_bounds__(1024) void scan_blocks_kernel(
    const int* __restrict__ counts, int* __restrict__ offsets,
    int* __restrict__ partials)
{
    __shared__ int sm[1024];
    const int t = threadIdx.x;
    const int gid = blockIdx.x * 1024 + t;
    const int v = (gid < N_NODES) ? counts[gid] : 0;
    sm[t] = v;
    __syncthreads();
    for (int off = 1; off < 1024; off <<= 1) {
        int a = (t >= off) ? sm[t - off] : 0;
        __syncthreads();
        sm[t] += a;
        __syncthreads();
    }
    if (gid < N_NODES) offsets[gid] = sm[t] - v;
    if (t == 1023) partials[blockIdx.x] = sm[1023];
}

__global__ __launch_bounds__(1024) void add_partials_kernel(
    const int* __restrict__ partials, int* __restrict__ offsets,
    int* __restrict__ cursor)
{
    const int blk = blockIdx.x;
    const int gid = blk * 1024 + threadIdx.x;
    int s = 0;
    for (int j = 0; j < blk; ++j) s += partials[j];
    if (gid < N_NODES) {
        const int o = offsets[gid] + s;
        offsets[gid] = o;
        cursor[gid]  = o;
    }
}

// meta[pos] = {edge_id, src}; ys[pos] = in2 row
__global__ void fill_kernel(const int* __restrict__ dst, const int* __restrict__ src,
                            const float4* __restrict__ in2,
                            int* __restrict__ cursor, int2* __restrict__ meta,
                            float4* __restrict__ ys) {
    int i = blockIdx.x * blockDim.x + threadIdx.x;
    if (i < N_EDGES) {
        int pos = atomicAdd(&cursor[dst[i]], 1);
        meta[pos] = make_int2(i, src[i]);
        ys[pos] = in2[i];
    }
}

// ---------------- main: 4 waves/node, 2 VMEM requests/edge via LDS staging ----------------
__global__ __launch_bounds__(256) void tp_node4c_kernel(
    const float*  __restrict__ in1,
    const float*  __restrict__ weight,
    const int*    __restrict__ offsets,
    const int2*   __restrict__ meta,
    const float4* __restrict__ ys,
    float*        __restrict__ out)
{
    __shared__ float xbuf[4][160];
    __shared__ float wbuf[4][224];
    __shared__ float sm[4][512];

    const int wave = threadIdx.x >> 6;
    const int lane = threadIdx.x & 63;
    const int n = blockIdx.x;
    const int u = lane & 31;
    const int h = lane >> 5;

    const int start = offsets[n];
    const int end   = (n + 1 < N_NODES) ? offsets[n + 1] : N_EDGES;

    float acc0 = 0.f, acc1 = 0.f, acc2 = 0.f, acc3 = 0.f;
    float acc4 = 0.f, acc5 = 0.f, acc6 = 0.f, acc7 = 0.f;

    float* __restrict__ xb = &xbuf[wave][0];
    float* __restrict__ wb = &wbuf[wave][0];

    for (int p = start + wave; p < end; p += 4) {
        // wave-uniform metadata via scalar path
        const int pu = __builtin_amdgcn_readfirstlane(p);
        const int2 m = meta[pu];
        const float4 yv = ys[pu];
        const float y0 = yv.x, yx = yv.y, yy = yv.z, yz = yv.w;

        // whole rows as single dwordx4 requests (exact-size, no overrun)
        const float4* __restrict__ xrow = (const float4*)(in1 + (long)m.y * IN1_SIZE);
        const float4* __restrict__ wrow = (const float4*)(weight + (long)m.x * W_SIZE);
        float4 xv, wv;
        if (lane < 40) xv = xrow[lane];     // 640 B = full x row
        if (lane < 56) wv = wrow[lane];     // 896 B = full w row

        // stage to per-wave LDS (no cross-wave sharing -> no barrier)
        if (lane < 40) *(float4*)(xb + 4 * lane) = xv;
        if (lane < 56) *(float4*)(wb + 4 * lane) = wv;

        // per-lane reads from LDS (conflict-free strides)
        const float xs = xb[lane];
        const float v0 = xb[64 + 3 * u];
        const float v1 = xb[65 + 3 * u];
        const float v2 = xb[66 + 3 * u];
        const float w1 = wb[lane];
        const float w2 = wb[64 + lane];
        const float w3 = wb[128 + u];
        const float w4 = wb[160 + u];
        const float w5 = wb[192 + u];

        acc0 += w1 * xs * y0;
        const float sw2 = w2 * xs;
        acc1 += sw2 * yx;
        acc2 += sw2 * yy;
        acc3 += sw2 * yz;
        if (h == 0) {
            acc4 += w4 * (v0 * yx + v1 * yy + v2 * yz) * INV_SQRT3;
            const float wy = w3 * y0;
            acc5 += wy * v0;
            acc6 += wy * v1;
            acc7 += wy * v2;
        } else {
            const float wc = w5 * INV_SQRT2;
            acc5 += wc * (v1 * yz - v2 * yy);
            acc6 += wc * (v2 * yx - v0 * yz);
            acc7 += wc * (v0 * yy - v1 * yx);
        }
    }

    // combine across the 4 waves via LDS
    float* smw = &sm[wave][0];
    smw[0 * 64 + lane] = acc0;
    smw[1 * 64 + lane] = acc1;
    smw[2 * 64 + lane] = acc2;
    smw[3 * 64 + lane] = acc3;
    smw[4 * 64 + lane] = acc4;
    smw[5 * 64 + lane] = acc5;
    smw[6 * 64 + lane] = acc6;
    smw[7 * 64 + lane] = acc7;
    __syncthreads();

    float* __restrict__ row = out + (long)n * OUT_SIZE;
    #pragma unroll
    for (int r = 0; r < 2; ++r) {
        const int s  = threadIdx.x + 256 * r;
        const int j  = s >> 6;
        const int l  = s & 63;
        const int uu = l & 31;
        const int hh = l >> 5;
        const float v = sm[0][s] + sm[1][s] + sm[2][s] + sm[3][s];
        int off;
        bool valid = true;
        if (j == 0)        off = l;
        else if (j <= 3)   off = 96 + 3 * l + (j - 1);
        else if (j == 4) { off = 64 + uu; valid = (hh == 0); }
        else               off = (hh ? 384 : 288) + 3 * uu + (j - 5);
        if (valid) row[off] = v;
    }
}

// ---------------- fallback path (R1, atomics, no ws needed) ----------------
__global__ void zero_out_kernel(float4* __restrict__ out, int n4) {
    const float4 z = make_float4(0.f, 0.f, 0.f, 0.f);
    for (int i = blockIdx.x * blockDim.x + threadIdx.x; i < n4;
         i += gridDim.x * blockDim.x) out[i] = z;
}

__device__ __forceinline__ float edge_val(
    int idx, const float* __restrict__ x, const float* __restrict__ w,
    float y0, float y1x, float y1y, float y1z)
{
    if (idx < 64) {
        return w[idx] * x[idx] * y0;
    } else if (idx < 96) {
        const int u = idx - 64;
        const float a0 = x[64 + 3 * u], a1 = x[65 + 3 * u], a2 = x[66 + 3 * u];
        return w[160 + u] * (a0 * y1x + a1 * y1y + a2 * y1z) * INV_SQRT3;
    } else if (idx < 288) {
        const int t = idx - 96;
        const int i = t / 3;
        const int k = t - 3 * i;
        const float yk = (k == 0) ? y1x : (k == 1) ? y1y : y1z;
        return w[64 + i] * x[i] * yk;
    } else if (idx < 384) {
        const int t = idx - 288;
        const int u = t / 3;
        const int k = t - 3 * u;
        return w[128 + u] * x[64 + 3 * u + k] * y0;
    } else {
        const int t = idx - 384;
        const int u = t / 3;
        const int k = t - 3 * u;
        const float a0 = x[64 + 3 * u], a1 = x[65 + 3 * u], a2 = x[66 + 3 * u];
        float cc;
        if (k == 0)      cc = a1 * y1z - a2 * y1y;
        else if (k == 1) cc = a2 * y1x - a0 * y1z;
        else             cc = a0 * y1y - a1 * y1x;
        return w[192 + u] * cc * INV_SQRT2;
    }
}

__global__ __launch_bounds__(256) void tp_scatter_kernel(
    const float* __restrict__ in1, const float* __restrict__ in2,
    const float* __restrict__ weight,
    const int* __restrict__ src, const int* __restrict__ dst,
    float* __restrict__ out)
{
    const int wave = threadIdx.x >> 6;
    const int lane = threadIdx.x & 63;
    const int e = blockIdx.x * 4 + wave;
    if (e >= N_EDGES) return;
    const int sn = src[e];
    const int dn = dst[e];
    const float* __restrict__ x = in1 + (long)sn * IN1_SIZE;
    const float* __restrict__ w = weight + (long)e * W_SIZE;
    const float y0  = in2[e * 4 + 0];
    const float y1x = in2[e * 4 + 1];
    const float y1y = in2[e * 4 + 2];
    const float y1z = in2[e * 4 + 3];
    float* __restrict__ o = out + (long)dn * OUT_SIZE;
    #pragma unroll
    for (int j = 0; j < 8; ++j) {
        const int idx = lane + (j << 6);
        if (idx < OUT_SIZE)
            atomicAdd(o + idx, edge_val(idx, x, w, y0, y1x, y1y, y1z));
    }
}

extern "C" void kernel_launch(void* const* d_in, const int* in_sizes, int n_in,
                              void* d_out, int out_size, void* d_ws, size_t ws_size,
                              hipStream_t stream) {
    const float* in1    = (const float*)d_in[0];
    const float* in2    = (const float*)d_in[1];
    const float* weight = (const float*)d_in[2];
    const int*   src    = (const int*)d_in[3];
    const int*   dst    = (const int*)d_in[4];
    float* out = (float*)d_out;

    // ws layout: ys[E] float4 | meta[E] int2 | counts[N] | offsets[N] | cursor[N] | partials[64]
    const size_t need = (size_t)N_EDGES * 16 + (size_t)N_EDGES * 8 +
                        (size_t)(3 * N_NODES + 64) * sizeof(int);
    if (ws_size >= need) {
        float4* ys     = (float4*)d_ws;
        int2*   meta   = (int2*)(ys + N_EDGES);
        int* counts    = (int*)(meta + N_EDGES);
        int* offsets   = counts + N_NODES;
        int* cursor    = offsets + N_NODES;
        int* partials  = cursor + N_NODES;

        const int nblk = (N_NODES + 1023) / 1024;   // 49

        hipMemsetAsync(counts, 0, N_NODES * sizeof(int), stream);
        hist_kernel<<<(N_EDGES + 255) / 256, 256, 0, stream>>>(dst, counts);
        scan_blocks_kernel<<<nblk, 1024, 0, stream>>>(counts, offsets, partials);
        add_partials_kernel<<<nblk, 1024, 0, stream>>>(partials, offsets, cursor);
        fill_kernel<<<(N_EDGES + 255) / 256, 256, 0, stream>>>(
            dst, src, (const float4*)in2, cursor, meta, ys);

        tp_node4c_kernel<<<N_NODES, 256, 0, stream>>>(
            in1, weight, offsets, meta, ys, out);
    } else {
        const int n4 = out_size / 4;
        zero_out_kernel<<<2048, 256, 0, stream>>>((float4*)out, n4);
        tp_scatter_kernel<<<(N_EDGES + 3) / 4, 256, 0, stream>>>(
            in1, in2, weight, src, dst, out);
    }
}

// Round 9
// 122.016 us; speedup vs baseline: 1.8001x; 1.0375x over previous
//
#include <hip/hip_runtime.h>

#define N_NODES 50000
#define N_EDGES 200000
#define IN1_SIZE 160
#define W_SIZE 224
#define OUT_SIZE 480
#define INV_SQRT3 0.5773502691896258f
#define INV_SQRT2 0.7071067811865476f

// ---------------- CSR build ----------------
__global__ void hist_kernel(const int* __restrict__ dst, int* __restrict__ counts) {
    int i = blockIdx.x * blockDim.x + threadIdx.x;
    if (i < N_EDGES) atomicAdd(&counts[dst[i]], 1);
}

__global__ __launch_bounds__(1024) void scan_blocks_kernel(
    const int* __restrict__ counts, int* __restrict__ offsets,
    int* __restrict__ partials)
{
    __shared__ int sm[1024];
    const int t = threadIdx.x;
    const int gid = blockIdx.x * 1024 + t;
    const int v = (gid < N_NODES) ? counts[gid] : 0;
    sm[t] = v;
    __syncthreads();
    for (int off = 1; off < 1024; off <<= 1) {
        int a = (t >= off) ? sm[t - off] : 0;
        __syncthreads();
        sm[t] += a;
        __syncthreads();
    }
    if (gid < N_NODES) offsets[gid] = sm[t] - v;
    if (t == 1023) partials[blockIdx.x] = sm[1023];
}

__global__ __launch_bounds__(1024) void add_partials_kernel(
    const int* __restrict__ partials, int* __restrict__ offsets,
    int* __restrict__ cursor)
{
    const int blk = blockIdx.x;
    const int gid = blk * 1024 + threadIdx.x;
    int s = 0;
    for (int j = 0; j < blk; ++j) s += partials[j];
    if (gid < N_NODES) {
        const int o = offsets[gid] + s;
        offsets[gid] = o;
        cursor[gid]  = o;
    }
}

// meta[pos] = {edge_id, src}; ys[pos] = in2 row
__global__ void fill_kernel(const int* __restrict__ dst, const int* __restrict__ src,
                            const float4* __restrict__ in2,
                            int* __restrict__ cursor, int2* __restrict__ meta,
                            float4* __restrict__ ys) {
    int i = blockIdx.x * blockDim.x + threadIdx.x;
    if (i < N_EDGES) {
        int pos = atomicAdd(&cursor[dst[i]], 1);
        meta[pos] = make_int2(i, src[i]);
        ys[pos] = in2[i];
    }
}

// ---------------- main: 4 waves/node, LDS staging, one-ahead pipelined loads ----------------
__global__ __launch_bounds__(256) void tp_node4d_kernel(
    const float*  __restrict__ in1,
    const float*  __restrict__ weight,
    const int*    __restrict__ offsets,
    const int2*   __restrict__ meta,
    const float4* __restrict__ ys,
    float*        __restrict__ out)
{
    __shared__ float xbuf[4][160];
    __shared__ float wbuf[4][224];
    __shared__ float sm[4][512];

    const int wave = threadIdx.x >> 6;
    const int lane = threadIdx.x & 63;
    const int n = blockIdx.x;
    const int u = lane & 31;
    const int h = lane >> 5;

    const int start = offsets[n];
    const int end   = (n + 1 < N_NODES) ? offsets[n + 1] : N_EDGES;

    float acc0 = 0.f, acc1 = 0.f, acc2 = 0.f, acc3 = 0.f;
    float acc4 = 0.f, acc5 = 0.f, acc6 = 0.f, acc7 = 0.f;

    float* __restrict__ xb = &xbuf[wave][0];
    float* __restrict__ wb = &wbuf[wave][0];

    int p = start + wave;

    // prologue: issue loads for first edge
    float4 xv = make_float4(0.f, 0.f, 0.f, 0.f);
    float4 wv = make_float4(0.f, 0.f, 0.f, 0.f);
    float4 yv = make_float4(0.f, 0.f, 0.f, 0.f);
    if (p < end) {
        const int pu = __builtin_amdgcn_readfirstlane(p);
        const int2 m = meta[pu];
        yv = ys[pu];
        const float4* __restrict__ xr = (const float4*)(in1 + (long)m.y * IN1_SIZE);
        const float4* __restrict__ wr = (const float4*)(weight + (long)m.x * W_SIZE);
        if (lane < 40) xv = xr[lane];
        if (lane < 56) wv = wr[lane];
    }

    for (; p < end; p += 4) {
        // issue NEXT edge's loads before consuming current (keeps ~2 edges in flight)
        const int pn = p + 4;
        float4 xvn = make_float4(0.f, 0.f, 0.f, 0.f);
        float4 wvn = make_float4(0.f, 0.f, 0.f, 0.f);
        float4 yvn = make_float4(0.f, 0.f, 0.f, 0.f);
        if (pn < end) {
            const int pun = __builtin_amdgcn_readfirstlane(pn);
            const int2 mn = meta[pun];
            yvn = ys[pun];
            const float4* __restrict__ xrn = (const float4*)(in1 + (long)mn.y * IN1_SIZE);
            const float4* __restrict__ wrn = (const float4*)(weight + (long)mn.x * W_SIZE);
            if (lane < 40) xvn = xrn[lane];
            if (lane < 56) wvn = wrn[lane];
        }

        // stage current edge to per-wave LDS (waits only on current's loads)
        if (lane < 40) *(float4*)(xb + 4 * lane) = xv;
        if (lane < 56) *(float4*)(wb + 4 * lane) = wv;

        // per-lane reads from LDS (in-order DS pipe: safe without barrier)
        const float xs = xb[lane];
        const float v0 = xb[64 + 3 * u];
        const float v1 = xb[65 + 3 * u];
        const float v2 = xb[66 + 3 * u];
        const float w1 = wb[lane];
        const float w2 = wb[64 + lane];
        const float w3 = wb[128 + u];
        const float w4 = wb[160 + u];
        const float w5 = wb[192 + u];

        const float y0 = yv.x, yx = yv.y, yy = yv.z, yz = yv.w;
        acc0 += w1 * xs * y0;
        const float sw2 = w2 * xs;
        acc1 += sw2 * yx;
        acc2 += sw2 * yy;
        acc3 += sw2 * yz;
        if (h == 0) {
            acc4 += w4 * (v0 * yx + v1 * yy + v2 * yz) * INV_SQRT3;
            const float wy = w3 * y0;
            acc5 += wy * v0;
            acc6 += wy * v1;
            acc7 += wy * v2;
        } else {
            const float wc = w5 * INV_SQRT2;
            acc5 += wc * (v1 * yz - v2 * yy);
            acc6 += wc * (v2 * yx - v0 * yz);
            acc7 += wc * (v0 * yy - v1 * yx);
        }

        // rotate pipeline registers
        xv = xvn;
        wv = wvn;
        yv = yvn;
    }

    // combine across the 4 waves via LDS
    float* smw = &sm[wave][0];
    smw[0 * 64 + lane] = acc0;
    smw[1 * 64 + lane] = acc1;
    smw[2 * 64 + lane] = acc2;
    smw[3 * 64 + lane] = acc3;
    smw[4 * 64 + lane] = acc4;
    smw[5 * 64 + lane] = acc5;
    smw[6 * 64 + lane] = acc6;
    smw[7 * 64 + lane] = acc7;
    __syncthreads();

    float* __restrict__ row = out + (long)n * OUT_SIZE;
    #pragma unroll
    for (int r = 0; r < 2; ++r) {
        const int s  = threadIdx.x + 256 * r;
        const int j  = s >> 6;
        const int l  = s & 63;
        const int uu = l & 31;
        const int hh = l >> 5;
        const float v = sm[0][s] + sm[1][s] + sm[2][s] + sm[3][s];
        int off;
        bool valid = true;
        if (j == 0)        off = l;
        else if (j <= 3)   off = 96 + 3 * l + (j - 1);
        else if (j == 4) { off = 64 + uu; valid = (hh == 0); }
        else               off = (hh ? 384 : 288) + 3 * uu + (j - 5);
        if (valid) row[off] = v;
    }
}

// ---------------- fallback path (R1, atomics, no ws needed) ----------------
__global__ void zero_out_kernel(float4* __restrict__ out, int n4) {
    const float4 z = make_float4(0.f, 0.f, 0.f, 0.f);
    for (int i = blockIdx.x * blockDim.x + threadIdx.x; i < n4;
         i += gridDim.x * blockDim.x) out[i] = z;
}

__device__ __forceinline__ float edge_val(
    int idx, const float* __restrict__ x, const float* __restrict__ w,
    float y0, float y1x, float y1y, float y1z)
{
    if (idx < 64) {
        return w[idx] * x[idx] * y0;
    } else if (idx < 96) {
        const int u = idx - 64;
        const float a0 = x[64 + 3 * u], a1 = x[65 + 3 * u], a2 = x[66 + 3 * u];
        return w[160 + u] * (a0 * y1x + a1 * y1y + a2 * y1z) * INV_SQRT3;
    } else if (idx < 288) {
        const int t = idx - 96;
        const int i = t / 3;
        const int k = t - 3 * i;
        const float yk = (k == 0) ? y1x : (k == 1) ? y1y : y1z;
        return w[64 + i] * x[i] * yk;
    } else if (idx < 384) {
        const int t = idx - 288;
        const int u = t / 3;
        const int k = t - 3 * u;
        return w[128 + u] * x[64 + 3 * u + k] * y0;
    } else {
        const int t = idx - 384;
        const int u = t / 3;
        const int k = t - 3 * u;
        const float a0 = x[64 + 3 * u], a1 = x[65 + 3 * u], a2 = x[66 + 3 * u];
        float cc;
        if (k == 0)      cc = a1 * y1z - a2 * y1y;
        else if (k == 1) cc = a2 * y1x - a0 * y1z;
        else             cc = a0 * y1y - a1 * y1x;
        return w[192 + u] * cc * INV_SQRT2;
    }
}

__global__ __launch_bounds__(256) void tp_scatter_kernel(
    const float* __restrict__ in1, const float* __restrict__ in2,
    const float* __restrict__ weight,
    const int* __restrict__ src, const int* __restrict__ dst,
    float* __restrict__ out)
{
    const int wave = threadIdx.x >> 6;
    const int lane = threadIdx.x & 63;
    const int e = blockIdx.x * 4 + wave;
    if (e >= N_EDGES) return;
    const int sn = src[e];
    const int dn = dst[e];
    const float* __restrict__ x = in1 + (long)sn * IN1_SIZE;
    const float* __restrict__ w = weight + (long)e * W_SIZE;
    const float y0  = in2[e * 4 + 0];
    const float y1x = in2[e * 4 + 1];
    const float y1y = in2[e * 4 + 2];
    const float y1z = in2[e * 4 + 3];
    float* __restrict__ o = out + (long)dn * OUT_SIZE;
    #pragma unroll
    for (int j = 0; j < 8; ++j) {
        const int idx = lane + (j << 6);
        if (idx < OUT_SIZE)
            atomicAdd(o + idx, edge_val(idx, x, w, y0, y1x, y1y, y1z));
    }
}

extern "C" void kernel_launch(void* const* d_in, const int* in_sizes, int n_in,
                              void* d_out, int out_size, void* d_ws, size_t ws_size,
                              hipStream_t stream) {
    const float* in1    = (const float*)d_in[0];
    const float* in2    = (const float*)d_in[1];
    const float* weight = (const float*)d_in[2];
    const int*   src    = (const int*)d_in[3];
    const int*   dst    = (const int*)d_in[4];
    float* out = (float*)d_out;

    // ws layout: ys[E] float4 | meta[E] int2 | counts[N] | offsets[N] | cursor[N] | partials[64]
    const size_t need = (size_t)N_EDGES * 16 + (size_t)N_EDGES * 8 +
                        (size_t)(3 * N_NODES + 64) * sizeof(int);
    if (ws_size >= need) {
        float4* ys     = (float4*)d_ws;
        int2*   meta   = (int2*)(ys + N_EDGES);
        int* counts    = (int*)(meta + N_EDGES);
        int* offsets   = counts + N_NODES;
        int* cursor    = offsets + N_NODES;
        int* partials  = cursor + N_NODES;

        const int nblk = (N_NODES + 1023) / 1024;   // 49

        hipMemsetAsync(counts, 0, N_NODES * sizeof(int), stream);
        hist_kernel<<<(N_EDGES + 255) / 256, 256, 0, stream>>>(dst, counts);
        scan_blocks_kernel<<<nblk, 1024, 0, stream>>>(counts, offsets, partials);
        add_partials_kernel<<<nblk, 1024, 0, stream>>>(partials, offsets, cursor);
        fill_kernel<<<(N_EDGES + 255) / 256, 256, 0, stream>>>(
            dst, src, (const float4*)in2, cursor, meta, ys);

        tp_node4d_kernel<<<N_NODES, 256, 0, stream>>>(
            in1, weight, offsets, meta, ys, out);
    } else {
        const int n4 = out_size / 4;
        zero_out_kernel<<<2048, 256, 0, stream>>>((float4*)out, n4);
        tp_scatter_kernel<<<(N_EDGES + 3) / 4, 256, 0, stream>>>(
            in1, in2, weight, src, dst, out);
    }
}

// Round 10
// 105.672 us; speedup vs baseline: 2.0786x; 1.1547x over previous
//
#include <hip/hip_runtime.h>

#define N_NODES 50000
#define N_EDGES 200000
#define IN1_SIZE 160
#define W_SIZE 224
#define OUT_SIZE 480
#define INV_SQRT3 0.5773502691896258f
#define INV_SQRT2 0.7071067811865476f

// ---------------- CSR build ----------------
__global__ void hist_kernel(const int* __restrict__ dst, int* __restrict__ counts) {
    int i = blockIdx.x * blockDim.x + threadIdx.x;
    if (i < N_EDGES) atomicAdd(&counts[dst[i]], 1);
}

__global__ __launch_bounds__(1024) void scan_blocks_kernel(
    const int* __restrict__ counts, int* __restrict__ offsets,
    int* __restrict__ partials)
{
    __shared__ int sm[1024];
    const int t = threadIdx.x;
    const int gid = blockIdx.x * 1024 + t;
    const int v = (gid < N_NODES) ? counts[gid] : 0;
    sm[t] = v;
    __syncthreads();
    for (int off = 1; off < 1024; off <<= 1) {
        int a = (t >= off) ? sm[t - off] : 0;
        __syncthreads();
        sm[t] += a;
        __syncthreads();
    }
    if (gid < N_NODES) offsets[gid] = sm[t] - v;
    if (t == 1023) partials[blockIdx.x] = sm[1023];
}

__global__ __launch_bounds__(1024) void add_partials_kernel(
    const int* __restrict__ partials, int* __restrict__ offsets,
    int* __restrict__ cursor)
{
    const int blk = blockIdx.x;
    const int gid = blk * 1024 + threadIdx.x;
    int s = 0;
    for (int j = 0; j < blk; ++j) s += partials[j];
    if (gid < N_NODES) {
        const int o = offsets[gid] + s;
        offsets[gid] = o;
        cursor[gid]  = o;
    }
}

// meta[pos] = {edge_id, src}; ys[pos] = in2 row
__global__ void fill_kernel(const int* __restrict__ dst, const int* __restrict__ src,
                            const float4* __restrict__ in2,
                            int* __restrict__ cursor, int2* __restrict__ meta,
                            float4* __restrict__ ys) {
    int i = blockIdx.x * blockDim.x + threadIdx.x;
    if (i < N_EDGES) {
        int pos = atomicAdd(&cursor[dst[i]], 1);
        meta[pos] = make_int2(i, src[i]);
        ys[pos] = in2[i];
    }
}

// ---------------- main: 4 waves/node, LDS staging, pipelined loads, NT stores ----------------
__global__ __launch_bounds__(256) void tp_node4e_kernel(
    const float*  __restrict__ in1,
    const float*  __restrict__ weight,
    const int*    __restrict__ offsets,
    const int2*   __restrict__ meta,
    const float4* __restrict__ ys,
    float*        __restrict__ out)
{
    __shared__ float xbuf[4][160];
    __shared__ float wbuf[4][224];
    __shared__ float sm[4][512];

    const int wave = threadIdx.x >> 6;
    const int lane = threadIdx.x & 63;
    const int n = blockIdx.x;
    const int u = lane & 31;
    const int h = lane >> 5;

    const int start = offsets[n];
    const int end   = (n + 1 < N_NODES) ? offsets[n + 1] : N_EDGES;

    float acc0 = 0.f, acc1 = 0.f, acc2 = 0.f, acc3 = 0.f;
    float acc4 = 0.f, acc5 = 0.f, acc6 = 0.f, acc7 = 0.f;

    float* __restrict__ xb = &xbuf[wave][0];
    float* __restrict__ wb = &wbuf[wave][0];

    int p = start + wave;

    // prologue: issue loads for first edge
    float4 xv = make_float4(0.f, 0.f, 0.f, 0.f);
    float4 wv = make_float4(0.f, 0.f, 0.f, 0.f);
    float4 yv = make_float4(0.f, 0.f, 0.f, 0.f);
    if (p < end) {
        const int pu = __builtin_amdgcn_readfirstlane(p);
        const int2 m = meta[pu];
        yv = ys[pu];
        const float4* __restrict__ xr = (const float4*)(in1 + (long)m.y * IN1_SIZE);
        const float4* __restrict__ wr = (const float4*)(weight + (long)m.x * W_SIZE);
        if (lane < 40) xv = xr[lane];
        if (lane < 56) wv = wr[lane];
    }

    for (; p < end; p += 4) {
        // issue NEXT edge's loads before consuming current
        const int pn = p + 4;
        float4 xvn = make_float4(0.f, 0.f, 0.f, 0.f);
        float4 wvn = make_float4(0.f, 0.f, 0.f, 0.f);
        float4 yvn = make_float4(0.f, 0.f, 0.f, 0.f);
        if (pn < end) {
            const int pun = __builtin_amdgcn_readfirstlane(pn);
            const int2 mn = meta[pun];
            yvn = ys[pun];
            const float4* __restrict__ xrn = (const float4*)(in1 + (long)mn.y * IN1_SIZE);
            const float4* __restrict__ wrn = (const float4*)(weight + (long)mn.x * W_SIZE);
            if (lane < 40) xvn = xrn[lane];
            if (lane < 56) wvn = wrn[lane];
        }

        // stage current edge to per-wave LDS
        if (lane < 40) *(float4*)(xb + 4 * lane) = xv;
        if (lane < 56) *(float4*)(wb + 4 * lane) = wv;

        // per-lane reads from LDS (in-order DS pipe per wave: no barrier needed)
        const float xs = xb[lane];
        const float v0 = xb[64 + 3 * u];
        const float v1 = xb[65 + 3 * u];
        const float v2 = xb[66 + 3 * u];
        const float w1 = wb[lane];
        const float w2 = wb[64 + lane];
        const float w3 = wb[128 + u];
        const float w4 = wb[160 + u];
        const float w5 = wb[192 + u];

        const float y0 = yv.x, yx = yv.y, yy = yv.z, yz = yv.w;
        acc0 += w1 * xs * y0;
        const float sw2 = w2 * xs;
        acc1 += sw2 * yx;
        acc2 += sw2 * yy;
        acc3 += sw2 * yz;
        if (h == 0) {
            acc4 += w4 * (v0 * yx + v1 * yy + v2 * yz) * INV_SQRT3;
            const float wy = w3 * y0;
            acc5 += wy * v0;
            acc6 += wy * v1;
            acc7 += wy * v2;
        } else {
            const float wc = w5 * INV_SQRT2;
            acc5 += wc * (v1 * yz - v2 * yy);
            acc6 += wc * (v2 * yx - v0 * yz);
            acc7 += wc * (v0 * yy - v1 * yx);
        }

        xv = xvn;
        wv = wvn;
        yv = yvn;
    }

    // combine across the 4 waves via LDS
    float* smw = &sm[wave][0];
    smw[0 * 64 + lane] = acc0;
    smw[1 * 64 + lane] = acc1;
    smw[2 * 64 + lane] = acc2;
    smw[3 * 64 + lane] = acc3;
    smw[4 * 64 + lane] = acc4;
    smw[5 * 64 + lane] = acc5;
    smw[6 * 64 + lane] = acc6;
    smw[7 * 64 + lane] = acc7;
    __syncthreads();

    // non-temporal stores: out is never re-read -> don't evict weight from L3
    float* __restrict__ row = out + (long)n * OUT_SIZE;
    #pragma unroll
    for (int r = 0; r < 2; ++r) {
        const int s  = threadIdx.x + 256 * r;
        const int j  = s >> 6;
        const int l  = s & 63;
        const int uu = l & 31;
        const int hh = l >> 5;
        const float v = sm[0][s] + sm[1][s] + sm[2][s] + sm[3][s];
        int off;
        bool valid = true;
        if (j == 0)        off = l;
        else if (j <= 3)   off = 96 + 3 * l + (j - 1);
        else if (j == 4) { off = 64 + uu; valid = (hh == 0); }
        else               off = (hh ? 384 : 288) + 3 * uu + (j - 5);
        if (valid) __builtin_nontemporal_store(v, row + off);
    }
}

// ---------------- fallback path (R1, atomics, no ws needed) ----------------
__global__ void zero_out_kernel(float4* __restrict__ out, int n4) {
    const float4 z = make_float4(0.f, 0.f, 0.f, 0.f);
    for (int i = blockIdx.x * blockDim.x + threadIdx.x; i < n4;
         i += gridDim.x * blockDim.x) out[i] = z;
}

__device__ __forceinline__ float edge_val(
    int idx, const float* __restrict__ x, const float* __restrict__ w,
    float y0, float y1x, float y1y, float y1z)
{
    if (idx < 64) {
        return w[idx] * x[idx] * y0;
    } else if (idx < 96) {
        const int u = idx - 64;
        const float a0 = x[64 + 3 * u], a1 = x[65 + 3 * u], a2 = x[66 + 3 * u];
        return w[160 + u] * (a0 * y1x + a1 * y1y + a2 * y1z) * INV_SQRT3;
    } else if (idx < 288) {
        const int t = idx - 96;
        const int i = t / 3;
        const int k = t - 3 * i;
        const float yk = (k == 0) ? y1x : (k == 1) ? y1y : y1z;
        return w[64 + i] * x[i] * yk;
    } else if (idx < 384) {
        const int t = idx - 288;
        const int u = t / 3;
        const int k = t - 3 * u;
        return w[128 + u] * x[64 + 3 * u + k] * y0;
    } else {
        const int t = idx - 384;
        const int u = t / 3;
        const int k = t - 3 * u;
        const float a0 = x[64 + 3 * u], a1 = x[65 + 3 * u], a2 = x[66 + 3 * u];
        float cc;
        if (k == 0)      cc = a1 * y1z - a2 * y1y;
        else if (k == 1) cc = a2 * y1x - a0 * y1z;
        else             cc = a0 * y1y - a1 * y1x;
        return w[192 + u] * cc * INV_SQRT2;
    }
}

__global__ __launch_bounds__(256) void tp_scatter_kernel(
    const float* __restrict__ in1, const float* __restrict__ in2,
    const float* __restrict__ weight,
    const int* __restrict__ src, const int* __restrict__ dst,
    float* __restrict__ out)
{
    const int wave = threadIdx.x >> 6;
    const int lane = threadIdx.x & 63;
    const int e = blockIdx.x * 4 + wave;
    if (e >= N_EDGES) return;
    const int sn = src[e];
    const int dn = dst[e];
    const float* __restrict__ x = in1 + (long)sn * IN1_SIZE;
    const float* __restrict__ w = weight + (long)e * W_SIZE;
    const float y0  = in2[e * 4 + 0];
    const float y1x = in2[e * 4 + 1];
    const float y1y = in2[e * 4 + 2];
    const float y1z = in2[e * 4 + 3];
    float* __restrict__ o = out + (long)dn * OUT_SIZE;
    #pragma unroll
    for (int j = 0; j < 8; ++j) {
        const int idx = lane + (j << 6);
        if (idx < OUT_SIZE)
            atomicAdd(o + idx, edge_val(idx, x, w, y0, y1x, y1y, y1z));
    }
}

extern "C" void kernel_launch(void* const* d_in, const int* in_sizes, int n_in,
                              void* d_out, int out_size, void* d_ws, size_t ws_size,
                              hipStream_t stream) {
    const float* in1    = (const float*)d_in[0];
    const float* in2    = (const float*)d_in[1];
    const float* weight = (const float*)d_in[2];
    const int*   src    = (const int*)d_in[3];
    const int*   dst    = (const int*)d_in[4];
    float* out = (float*)d_out;

    // ws layout: ys[E] float4 | meta[E] int2 | counts[N] | offsets[N] | cursor[N] | partials[64]
    const size_t need = (size_t)N_EDGES * 16 + (size_t)N_EDGES * 8 +
                        (size_t)(3 * N_NODES + 64) * sizeof(int);
    if (ws_size >= need) {
        float4* ys     = (float4*)d_ws;
        int2*   meta   = (int2*)(ys + N_EDGES);
        int* counts    = (int*)(meta + N_EDGES);
        int* offsets   = counts + N_NODES;
        int* cursor    = offsets + N_NODES;
        int* partials  = cursor + N_NODES;

        const int nblk = (N_NODES + 1023) / 1024;   // 49

        hipMemsetAsync(counts, 0, N_NODES * sizeof(int), stream);
        hist_kernel<<<(N_EDGES + 255) / 256, 256, 0, stream>>>(dst, counts);
        scan_blocks_kernel<<<nblk, 1024, 0, stream>>>(counts, offsets, partials);
        add_partials_kernel<<<nblk, 1024, 0, stream>>>(partials, offsets, cursor);
        fill_kernel<<<(N_EDGES + 255) / 256, 256, 0, stream>>>(
            dst, src, (const float4*)in2, cursor, meta, ys);

        tp_node4e_kernel<<<N_NODES, 256, 0, stream>>>(
            in1, weight, offsets, meta, ys, out);
    } else {
        const int n4 = out_size / 4;
        zero_out_kernel<<<2048, 256, 0, stream>>>((float4*)out, n4);
        tp_scatter_kernel<<<(N_EDGES + 3) / 4, 256, 0, stream>>>(
            in1, in2, weight, src, dst, out);
    }
}